// Round 2
// baseline (263.569 us; speedup 1.0000x reference)
//
#include <hip/hip_runtime.h>
#include <hip/hip_bf16.h>

#define T_TOK 2048
#define E_DIM 1024
#define F_DIM 2048
#define N_EXP 8

typedef __attribute__((ext_vector_type(8))) short short8;
typedef __attribute__((ext_vector_type(4))) float f32x4;
typedef __attribute__((ext_vector_type(16))) float f32x16;

// swizzle for 4-chunk (64B) LDS rows: distinct over 8 consecutive rows (reads)
// and over n=4*uf+j write groups (writes) -> <=2-way read, <=4-way write conflicts
#define SWZ2(r) ((((r) & 3) ^ (((r) >> 2) & 3)))

__device__ __forceinline__ short bf2s(__hip_bfloat16 v) {
  union { __hip_bfloat16 b; short s; } u; u.b = v; return u.s;
}

__device__ __forceinline__ void gload_lds16(const void* g, void* l) {
  __builtin_amdgcn_global_load_lds((const __attribute__((address_space(1))) void*)g,
                                   (__attribute__((address_space(3))) void*)l, 16, 0, 0);
}

// ---------------- x fp32 -> bf16 ----------------
__global__ __launch_bounds__(256) void convert_x_kernel(const float* __restrict__ x,
                                                        __hip_bfloat16* __restrict__ xb) {
  size_t i = ((size_t)blockIdx.x * 256 + threadIdx.x) * 8;
  float4 a = *(const float4*)(x + i);
  float4 b = *(const float4*)(x + i + 4);
  short8 o;
  o[0] = bf2s(__float2bfloat16(a.x)); o[1] = bf2s(__float2bfloat16(a.y));
  o[2] = bf2s(__float2bfloat16(a.z)); o[3] = bf2s(__float2bfloat16(a.w));
  o[4] = bf2s(__float2bfloat16(b.x)); o[5] = bf2s(__float2bfloat16(b.y));
  o[6] = bf2s(__float2bfloat16(b.z)); o[7] = bf2s(__float2bfloat16(b.w));
  *(short8*)(xb + i) = o;
}

// ---------------- router: fp64 logits, top-2, softmax ----------------
__global__ __launch_bounds__(256) void router_kernel(const float* __restrict__ x,
                                                     const float* __restrict__ gk,
                                                     int* __restrict__ tk_e,
                                                     float* __restrict__ tk_p,
                                                     int* __restrict__ counts) {
  int w = threadIdx.x >> 6, l = threadIdx.x & 63;
  int t = blockIdx.x * 4 + w;
  const float* xr = x + (size_t)t * E_DIM;
  double acc[N_EXP];
#pragma unroll
  for (int n = 0; n < N_EXP; n++) acc[n] = 0.0;
  for (int j = 0; j < 16; j++) {
    int i = j * 64 + l;
    double xv = (double)xr[i];
    const float* g = gk + (size_t)i * N_EXP;
#pragma unroll
    for (int n = 0; n < N_EXP; n++) acc[n] += xv * (double)g[n];
  }
#pragma unroll
  for (int off = 32; off > 0; off >>= 1) {
#pragma unroll
    for (int n = 0; n < N_EXP; n++) acc[n] += __shfl_down(acc[n], off);
  }
  if (l == 0) {
    int e1 = 0; double v1 = acc[0];
    for (int n = 1; n < N_EXP; n++) if (acc[n] > v1) { v1 = acc[n]; e1 = n; }
    int e2 = -1; double v2 = -1e300;
    for (int n = 0; n < N_EXP; n++) if (n != e1 && acc[n] > v2) { v2 = acc[n]; e2 = n; }
    float ex = __expf((float)(v2 - v1));     // <= 1
    float p1 = 1.f / (1.f + ex);
    float p2 = ex / (1.f + ex);
    tk_e[t * 2 + 0] = e1; tk_p[t * 2 + 0] = p1;
    tk_e[t * 2 + 1] = e2; tk_p[t * 2 + 1] = p2;
    atomicAdd(&counts[e1], 1);
    atomicAdd(&counts[e2], 1);
  }
}

// ---------------- scan: offsets + m-tile table ----------------
// ctrl ints: [0..7] counts, [8..15] cursors, [16..23] offs, [24] ntiles,
//            [32..95] tbl_e, [96..159] tbl_slot0, [160..223] tbl_rows
__global__ void scan_kernel(int* ctrl) {
  if (threadIdx.x != 0) return;
  int off = 0, idx = 0;
  for (int e = 0; e < N_EXP; e++) {
    ctrl[16 + e] = off;
    int c = ctrl[e];
    for (int m0 = 0; m0 < c; m0 += 128) {
      ctrl[32 + idx] = e;
      ctrl[96 + idx] = off + m0;
      ctrl[160 + idx] = (c - m0 < 128) ? (c - m0) : 128;
      idx++;
    }
    off += c;
  }
  ctrl[24] = idx;
}

// ---------------- permute: build slot lists ----------------
__global__ __launch_bounds__(256) void permute_kernel(const int* __restrict__ tk_e,
                                                      const float* __restrict__ tk_p,
                                                      int* __restrict__ ctrl,
                                                      int* __restrict__ slot_tok,
                                                      float* __restrict__ slot_prob) {
  int g = blockIdx.x * 256 + threadIdx.x;   // 0..4095
  int e = tk_e[g];
  float p = tk_p[g];
  int pos = atomicAdd(&ctrl[8 + e], 1);
  int slot = ctrl[16 + e] + pos;
  slot_tok[slot] = g >> 1;
  slot_prob[slot] = p;
}

// ---------------- GEMM1: h = silu(X@w0)*(X@w1); fused fp32->bf16 transpose-staging ----------------
// BM=128 BN=128 BK=32, 4 waves 64x64, mfma 32x32x16, 2-phase dbuf, 1 barrier/K-step
__global__ __launch_bounds__(256, 2) void gemm1_kernel(const __hip_bfloat16* __restrict__ xb,
                                                       const float* __restrict__ w0,
                                                       const float* __restrict__ w1,
                                                       const int* __restrict__ ctrl,
                                                       const int* __restrict__ slot_tok,
                                                       __hip_bfloat16* __restrict__ h) {
  int lin = blockIdx.x;                         // 640 = 8 * 80
  int logical = (lin & 7) * 80 + (lin >> 3);    // XCD-chunked
  int mt = logical % 40;
  int fy = logical / 40;                        // 0..15
  if (mt >= ctrl[24]) return;
  int e = ctrl[32 + mt];
  int slot0 = ctrl[96 + mt];
  int rowsv = ctrl[160 + mt];
  int f0 = fy * 128;

  __shared__ short lA[2][128 * 32];
  __shared__ short lB[2][2][128 * 32];

  int tid = threadIdx.x;
  int w = tid >> 6, l = tid & 63;
  int wm = w >> 1, wn = w & 1;

  // A staging (global_load_lds, pre-swizzled source)
  int rA1 = w * 32 + (l >> 2);
  int rA2 = rA1 + 16;
  int cg1 = (l & 3) ^ SWZ2(rA1);
  int cg2 = (l & 3) ^ SWZ2(rA2);
  int tok1 = slot_tok[slot0 + rA1];
  int tok2 = slot_tok[slot0 + rA2];
  const __hip_bfloat16* as1 = xb + (size_t)tok1 * E_DIM + cg1 * 8;
  const __hip_bfloat16* as2 = xb + (size_t)tok2 * E_DIM + cg2 * 8;

  // B staging (reg -> cvt -> transposed ds_write)
  int uf = tid & 31, uk = tid >> 5;
  const float* b0s = w0 + ((size_t)e * E_DIM + uk * 4) * F_DIM + f0 + uf * 4;
  const float* b1s = w1 + ((size_t)e * E_DIM + uk * 4) * F_DIM + f0 + uf * 4;

  float4 r0[4], r1[4];

  f32x16 acc0[2][2], acc1[2][2];
#pragma unroll
  for (int mi = 0; mi < 2; mi++)
#pragma unroll
    for (int ni = 0; ni < 2; ni++) {
#pragma unroll
      for (int q = 0; q < 16; q++) { acc0[mi][ni][q] = 0.f; acc1[mi][ni][q] = 0.f; }
    }

  auto stageA = [&](int k0, int buf) {
    gload_lds16(as1 + k0, &lA[buf][(w * 32) * 32]);
    gload_lds16(as2 + k0, &lA[buf][(w * 32 + 16) * 32]);
  };
  auto loadB = [&](int k0) {
#pragma unroll
    for (int r = 0; r < 4; ++r) {
      r0[r] = *(const float4*)(b0s + (size_t)(k0 + r) * F_DIM);
      r1[r] = *(const float4*)(b1s + (size_t)(k0 + r) * F_DIM);
    }
  };
  auto writeB = [&](int buf) {
#pragma unroll
    for (int j = 0; j < 4; ++j) {
      int n = uf * 4 + j;
      int el = n * 32 + (((uk >> 1) ^ SWZ2(n)) & 3) * 8 + (uk & 1) * 4;
      short4 q0, q1;
      q0.x = bf2s(__float2bfloat16(((const float*)&r0[0])[j]));
      q0.y = bf2s(__float2bfloat16(((const float*)&r0[1])[j]));
      q0.z = bf2s(__float2bfloat16(((const float*)&r0[2])[j]));
      q0.w = bf2s(__float2bfloat16(((const float*)&r0[3])[j]));
      q1.x = bf2s(__float2bfloat16(((const float*)&r1[0])[j]));
      q1.y = bf2s(__float2bfloat16(((const float*)&r1[1])[j]));
      q1.z = bf2s(__float2bfloat16(((const float*)&r1[2])[j]));
      q1.w = bf2s(__float2bfloat16(((const float*)&r1[3])[j]));
      *(short4*)&lB[buf][0][el] = q0;
      *(short4*)&lB[buf][1][el] = q1;
    }
  };
  auto compute = [&](int buf) {
#pragma unroll
    for (int ks = 0; ks < 2; ++ks) {
      int cb = 2 * ks + (l >> 5);
      short8 af[2], b0f[2], b1f[2];
#pragma unroll
      for (int mi = 0; mi < 2; ++mi) {
        int r = wm * 64 + mi * 32 + (l & 31);
        af[mi] = *(const short8*)&lA[buf][r * 32 + ((cb ^ SWZ2(r)) & 3) * 8];
      }
#pragma unroll
      for (int ni = 0; ni < 2; ++ni) {
        int n = wn * 64 + ni * 32 + (l & 31);
        int el = n * 32 + ((cb ^ SWZ2(n)) & 3) * 8;
        b0f[ni] = *(const short8*)&lB[buf][0][el];
        b1f[ni] = *(const short8*)&lB[buf][1][el];
      }
#pragma unroll
      for (int mi = 0; mi < 2; ++mi)
#pragma unroll
        for (int ni = 0; ni < 2; ++ni) {
          acc0[mi][ni] = __builtin_amdgcn_mfma_f32_32x32x16_bf16(af[mi], b0f[ni], acc0[mi][ni], 0, 0, 0);
          acc1[mi][ni] = __builtin_amdgcn_mfma_f32_32x32x16_bf16(af[mi], b1f[ni], acc1[mi][ni], 0, 0, 0);
        }
    }
  };

  // prologue
  stageA(0, 0); loadB(0); writeB(0);
  __syncthreads();

  const int NT = E_DIM / 32;
  for (int t = 0; t < NT; ++t) {
    int cur = t & 1;
    if (t + 1 < NT) { stageA((t + 1) * 32, cur ^ 1); loadB((t + 1) * 32); }
    compute(cur);
    if (t + 1 < NT) writeB(cur ^ 1);
    __syncthreads();
  }

  // epilogue: silu(acc0)*acc1 -> h (bf16)
  int hi = l >> 5, cl = l & 31;
#pragma unroll
  for (int mi = 0; mi < 2; ++mi) {
#pragma unroll
    for (int reg = 0; reg < 16; ++reg) {
      int row = wm * 64 + mi * 32 + 4 * hi + (reg & 3) + 8 * (reg >> 2);
      if (row < rowsv) {
        __hip_bfloat16* hr = h + (size_t)(slot0 + row) * F_DIM + f0 + wn * 64;
#pragma unroll
        for (int ni = 0; ni < 2; ++ni) {
          float v0 = acc0[mi][ni][reg];
          float v1 = acc1[mi][ni][reg];
          float s = (v0 / (1.f + __expf(-v0))) * v1;
          hr[ni * 32 + cl] = __float2bfloat16(s);
        }
      }
    }
  }
}

// ---------------- GEMM2: out += p * (h @ wo); fused fp32->bf16 transpose-staging ----------------
__global__ __launch_bounds__(256, 2) void gemm2_kernel(const __hip_bfloat16* __restrict__ h,
                                                       const float* __restrict__ wo,
                                                       const int* __restrict__ ctrl,
                                                       const int* __restrict__ slot_tok,
                                                       const float* __restrict__ slot_prob,
                                                       float* __restrict__ out) {
  int lin = blockIdx.x;                         // 320 = 8 * 40
  int logical = (lin & 7) * 40 + (lin >> 3);
  int mt = logical % 40;
  int ey = logical / 40;                        // 0..7
  if (mt >= ctrl[24]) return;
  int e = ctrl[32 + mt];
  int slot0 = ctrl[96 + mt];
  int rowsv = ctrl[160 + mt];
  int e0 = ey * 128;

  __shared__ short lA[2][128 * 32];
  __shared__ short lB[2][128 * 32];

  int tid = threadIdx.x;
  int w = tid >> 6, l = tid & 63;
  int wm = w >> 1, wn = w & 1;

  int rA1 = w * 32 + (l >> 2);
  int rA2 = rA1 + 16;
  int cg1 = (l & 3) ^ SWZ2(rA1);
  int cg2 = (l & 3) ^ SWZ2(rA2);
  const __hip_bfloat16* as1 = h + (size_t)(slot0 + rA1) * F_DIM + cg1 * 8;
  const __hip_bfloat16* as2 = h + (size_t)(slot0 + rA2) * F_DIM + cg2 * 8;

  int uf = tid & 31, uk = tid >> 5;
  const float* bs = wo + ((size_t)e * F_DIM + uk * 4) * E_DIM + e0 + uf * 4;

  float4 rb[4];

  f32x16 acc[2][2];
#pragma unroll
  for (int mi = 0; mi < 2; mi++)
#pragma unroll
    for (int ni = 0; ni < 2; ni++)
#pragma unroll
      for (int q = 0; q < 16; q++) acc[mi][ni][q] = 0.f;

  auto stageA = [&](int k0, int buf) {
    gload_lds16(as1 + k0, &lA[buf][(w * 32) * 32]);
    gload_lds16(as2 + k0, &lA[buf][(w * 32 + 16) * 32]);
  };
  auto loadB = [&](int k0) {
#pragma unroll
    for (int r = 0; r < 4; ++r)
      rb[r] = *(const float4*)(bs + (size_t)(k0 + r) * E_DIM);
  };
  auto writeB = [&](int buf) {
#pragma unroll
    for (int j = 0; j < 4; ++j) {
      int n = uf * 4 + j;
      int el = n * 32 + (((uk >> 1) ^ SWZ2(n)) & 3) * 8 + (uk & 1) * 4;
      short4 q0;
      q0.x = bf2s(__float2bfloat16(((const float*)&rb[0])[j]));
      q0.y = bf2s(__float2bfloat16(((const float*)&rb[1])[j]));
      q0.z = bf2s(__float2bfloat16(((const float*)&rb[2])[j]));
      q0.w = bf2s(__float2bfloat16(((const float*)&rb[3])[j]));
      *(short4*)&lB[buf][el] = q0;
    }
  };
  auto compute = [&](int buf) {
#pragma unroll
    for (int ks = 0; ks < 2; ++ks) {
      int cb = 2 * ks + (l >> 5);
      short8 af[2], bf[2];
#pragma unroll
      for (int mi = 0; mi < 2; ++mi) {
        int r = wm * 64 + mi * 32 + (l & 31);
        af[mi] = *(const short8*)&lA[buf][r * 32 + ((cb ^ SWZ2(r)) & 3) * 8];
      }
#pragma unroll
      for (int ni = 0; ni < 2; ++ni) {
        int n = wn * 64 + ni * 32 + (l & 31);
        bf[ni] = *(const short8*)&lB[buf][n * 32 + ((cb ^ SWZ2(n)) & 3) * 8];
      }
#pragma unroll
      for (int mi = 0; mi < 2; ++mi)
#pragma unroll
        for (int ni = 0; ni < 2; ++ni)
          acc[mi][ni] = __builtin_amdgcn_mfma_f32_32x32x16_bf16(af[mi], bf[ni], acc[mi][ni], 0, 0, 0);
    }
  };

  stageA(0, 0); loadB(0); writeB(0);
  __syncthreads();

  const int NT = F_DIM / 32;
  for (int t = 0; t < NT; ++t) {
    int cur = t & 1;
    if (t + 1 < NT) { stageA((t + 1) * 32, cur ^ 1); loadB((t + 1) * 32); }
    compute(cur);
    if (t + 1 < NT) writeB(cur ^ 1);
    __syncthreads();
  }

  int hi = l >> 5, cl = l & 31;
#pragma unroll
  for (int mi = 0; mi < 2; ++mi) {
#pragma unroll
    for (int reg = 0; reg < 16; ++reg) {
      int row = wm * 64 + mi * 32 + 4 * hi + (reg & 3) + 8 * (reg >> 2);
      if (row < rowsv) {
        int slot = slot0 + row;
        int tk = slot_tok[slot];
        float p = slot_prob[slot];
        float* orow = out + (size_t)tk * E_DIM + e0 + wn * 64;
#pragma unroll
        for (int ni = 0; ni < 2; ++ni)
          atomicAdd(&orow[ni * 32 + cl], p * acc[mi][ni][reg]);
      }
    }
  }
}

extern "C" void kernel_launch(void* const* d_in, const int* in_sizes, int n_in,
                              void* d_out, int out_size, void* d_ws, size_t ws_size,
                              hipStream_t stream) {
  const float* x  = (const float*)d_in[0];
  const float* gk = (const float*)d_in[1];
  const float* w0 = (const float*)d_in[2];
  const float* w1 = (const float*)d_in[3];
  const float* wo = (const float*)d_in[4];
  float* out = (float*)d_out;
  char* ws = (char*)d_ws;

  const size_t OFF_XB   = 0;
  const size_t OFF_H    = OFF_XB + (size_t)T_TOK * E_DIM * 2;
  const size_t OFF_STOK = OFF_H + (size_t)(4096 + 128) * F_DIM * 2;
  const size_t OFF_SPRB = OFF_STOK + (size_t)(4096 + 128) * 4;
  const size_t OFF_TKE  = OFF_SPRB + (size_t)(4096 + 128) * 4;
  const size_t OFF_TKP  = OFF_TKE + 4096 * 4;
  const size_t OFF_CTRL = OFF_TKP + 4096 * 4;
  const size_t NEED     = OFF_CTRL + 1024;
  if (ws_size < NEED) return;

  __hip_bfloat16* xb   = (__hip_bfloat16*)(ws + OFF_XB);
  __hip_bfloat16* hbuf = (__hip_bfloat16*)(ws + OFF_H);
  int*   slot_tok  = (int*)(ws + OFF_STOK);
  float* slot_prob = (float*)(ws + OFF_SPRB);
  int*   tk_e      = (int*)(ws + OFF_TKE);
  float* tk_p      = (float*)(ws + OFF_TKP);
  int*   ctrl      = (int*)(ws + OFF_CTRL);

  hipMemsetAsync(d_out, 0, (size_t)out_size * 4, stream);
  hipMemsetAsync(ctrl, 0, 1024, stream);
  hipMemsetAsync(slot_tok + 4096, 0, 128 * 4, stream);

  convert_x_kernel<<<(T_TOK * E_DIM) / (256 * 8), 256, 0, stream>>>(x, xb);
  router_kernel<<<T_TOK / 4, 256, 0, stream>>>(x, gk, tk_e, tk_p, ctrl);
  scan_kernel<<<1, 64, 0, stream>>>(ctrl);
  permute_kernel<<<4096 / 256, 256, 0, stream>>>(tk_e, tk_p, ctrl, slot_tok, slot_prob);
  gemm1_kernel<<<dim3(640), 256, 0, stream>>>(xb, w0, w1, ctrl, slot_tok, hbuf);
  gemm2_kernel<<<dim3(320), 256, 0, stream>>>(hbuf, wo, ctrl, slot_tok, slot_prob, out);
}

// Round 3
// 247.664 us; speedup vs baseline: 1.0642x; 1.0642x over previous
//
#include <hip/hip_runtime.h>
#include <hip/hip_bf16.h>

#define T_TOK 2048
#define E_DIM 1024
#define F_DIM 2048
#define N_EXP 8

typedef __attribute__((ext_vector_type(8))) short short8;
typedef __attribute__((ext_vector_type(4))) float f32x4;

__device__ __forceinline__ short bf2s(__hip_bfloat16 v) {
  union { __hip_bfloat16 b; short s; } u; u.b = v; return u.s;
}

__device__ __forceinline__ void gload_lds16(const void* g, void* l) {
  __builtin_amdgcn_global_load_lds((const __attribute__((address_space(1))) void*)g,
                                   (__attribute__((address_space(3))) void*)l, 16, 0, 0);
}

// ---------------- x fp32 -> bf16 ----------------
__global__ __launch_bounds__(256) void convert_x_kernel(const float* __restrict__ x,
                                                        __hip_bfloat16* __restrict__ xb) {
  size_t i = ((size_t)blockIdx.x * 256 + threadIdx.x) * 8;
  float4 a = *(const float4*)(x + i);
  float4 b = *(const float4*)(x + i + 4);
  short8 o;
  o[0] = bf2s(__float2bfloat16(a.x)); o[1] = bf2s(__float2bfloat16(a.y));
  o[2] = bf2s(__float2bfloat16(a.z)); o[3] = bf2s(__float2bfloat16(a.w));
  o[4] = bf2s(__float2bfloat16(b.x)); o[5] = bf2s(__float2bfloat16(b.y));
  o[6] = bf2s(__float2bfloat16(b.z)); o[7] = bf2s(__float2bfloat16(b.w));
  *(short8*)(xb + i) = o;
}

// ------------- merged transpose+convert: fp32 [R][C] -> bf16 [C][R] -------------
// z 0..7: w0 (R=E,C=F); z 8..15: w1; z 16..23: wo (R=F,C=E)
__global__ __launch_bounds__(256) void transpose_all_kernel(const float* __restrict__ w0,
                                                            const float* __restrict__ w1,
                                                            const float* __restrict__ wo,
                                                            __hip_bfloat16* __restrict__ w0t,
                                                            __hip_bfloat16* __restrict__ w1t,
                                                            __hip_bfloat16* __restrict__ wot) {
  __shared__ __hip_bfloat16 lt[64][72];
  int z = blockIdx.z;
  const float* src; __hip_bfloat16* dst;
  int R, C, r0, c0;
  if (z < 16) {
    R = E_DIM; C = F_DIM;
    int e = z & 7;
    src = (z < 8 ? w0 : w1) + (size_t)e * R * C;
    dst = (z < 8 ? w0t : w1t) + (size_t)e * R * C;
    r0 = blockIdx.y * 64; c0 = blockIdx.x * 64;
  } else {
    R = F_DIM; C = E_DIM;
    int e = z - 16;
    src = wo + (size_t)e * R * C;
    dst = wot + (size_t)e * R * C;
    c0 = (blockIdx.x & 15) * 64;
    r0 = (blockIdx.y * 2 + (blockIdx.x >> 4)) * 64;
  }
  int tid = threadIdx.x;
#pragma unroll
  for (int i = 0; i < 4; i++) {
    int chunk = i * 256 + tid;
    int r = chunk >> 4, c4 = (chunk & 15) * 4;
    float4 v = *(const float4*)(src + (size_t)(r0 + r) * C + c0 + c4);
    lt[r][c4 + 0] = __float2bfloat16(v.x);
    lt[r][c4 + 1] = __float2bfloat16(v.y);
    lt[r][c4 + 2] = __float2bfloat16(v.z);
    lt[r][c4 + 3] = __float2bfloat16(v.w);
  }
  __syncthreads();
#pragma unroll
  for (int i = 0; i < 2; i++) {
    int chunk = i * 256 + tid;
    int c = chunk >> 3, rr = (chunk & 7) * 8;
    short8 o;
#pragma unroll
    for (int j = 0; j < 8; j++) o[j] = bf2s(lt[rr + j][c]);
    *(short8*)(dst + (size_t)(c0 + c) * R + r0 + rr) = o;
  }
}

// ---------------- router: fp64 logits, top-2, softmax ----------------
__global__ __launch_bounds__(256) void router_kernel(const float* __restrict__ x,
                                                     const float* __restrict__ gk,
                                                     int* __restrict__ tk_e,
                                                     float* __restrict__ tk_p,
                                                     int* __restrict__ counts) {
  int w = threadIdx.x >> 6, l = threadIdx.x & 63;
  int t = blockIdx.x * 4 + w;
  const float* xr = x + (size_t)t * E_DIM;
  double acc[N_EXP];
#pragma unroll
  for (int n = 0; n < N_EXP; n++) acc[n] = 0.0;
  for (int j = 0; j < 16; j++) {
    int i = j * 64 + l;
    double xv = (double)xr[i];
    const float* g = gk + (size_t)i * N_EXP;
#pragma unroll
    for (int n = 0; n < N_EXP; n++) acc[n] += xv * (double)g[n];
  }
#pragma unroll
  for (int off = 32; off > 0; off >>= 1) {
#pragma unroll
    for (int n = 0; n < N_EXP; n++) acc[n] += __shfl_down(acc[n], off);
  }
  if (l == 0) {
    int e1 = 0; double v1 = acc[0];
    for (int n = 1; n < N_EXP; n++) if (acc[n] > v1) { v1 = acc[n]; e1 = n; }
    int e2 = -1; double v2 = -1e300;
    for (int n = 0; n < N_EXP; n++) if (n != e1 && acc[n] > v2) { v2 = acc[n]; e2 = n; }
    float ex = __expf((float)(v2 - v1));     // <= 1
    float p1 = 1.f / (1.f + ex);
    float p2 = ex / (1.f + ex);
    tk_e[t * 2 + 0] = e1; tk_p[t * 2 + 0] = p1;
    tk_e[t * 2 + 1] = e2; tk_p[t * 2 + 1] = p2;
    atomicAdd(&counts[e1], 1);
    atomicAdd(&counts[e2], 1);
  }
}

// ---------------- scan + permute, single block ----------------
// ctrl ints: [0..7] counts, [24] ntiles, [32..95] tbl_e, [96..159] tbl_slot0, [160..223] tbl_rows
__global__ __launch_bounds__(256) void scanperm_kernel(const int* __restrict__ tk_e,
                                                       const float* __restrict__ tk_p,
                                                       int* __restrict__ ctrl,
                                                       int* __restrict__ slot_tok,
                                                       float* __restrict__ slot_prob,
                                                       int* __restrict__ inv) {
  __shared__ int offs[8], cur[8];
  int tid = threadIdx.x;
  if (tid == 0) {
    int off = 0, idx = 0;
    for (int e = 0; e < N_EXP; e++) {
      offs[e] = off; cur[e] = 0;
      int c = ctrl[e];
      for (int m0 = 0; m0 < c; m0 += 128) {
        ctrl[32 + idx] = e;
        ctrl[96 + idx] = off + m0;
        ctrl[160 + idx] = (c - m0 < 128) ? (c - m0) : 128;
        idx++;
      }
      off += c;
    }
    ctrl[24] = idx;
  }
  __syncthreads();
  for (int g = tid; g < 2 * T_TOK; g += 256) {
    int e = tk_e[g];
    float p = tk_p[g];
    int pos = atomicAdd(&cur[e], 1);
    int slot = offs[e] + pos;
    slot_tok[slot] = g >> 1;
    slot_prob[slot] = p;
    inv[g] = slot;
  }
}

// ---------------- GEMM1: h = silu(X@w0)*(X@w1) ----------------
// 512 thr (8 waves, 2m x 4n), BM=128 BN=128 BK=64, dual B, dbuf LDS, 1 barrier/K-step
__global__ __launch_bounds__(512, 2) void gemm1_kernel(const __hip_bfloat16* __restrict__ xb,
                                                       const __hip_bfloat16* __restrict__ w0t,
                                                       const __hip_bfloat16* __restrict__ w1t,
                                                       const int* __restrict__ ctrl,
                                                       const int* __restrict__ slot_tok,
                                                       __hip_bfloat16* __restrict__ h) {
  int lin = blockIdx.x;                         // 640 = 8 * 80
  int logical = (lin & 7) * 80 + (lin >> 3);    // XCD-chunked
  int mt = logical % 40;
  int fy = logical / 40;                        // 0..15
  if (mt >= ctrl[24]) return;
  int e = ctrl[32 + mt];
  int slot0 = ctrl[96 + mt];
  int rowsv = ctrl[160 + mt];
  int f0 = fy * 128;

  __shared__ alignas(16) short lA[2][128 * 64];
  __shared__ alignas(16) short lB0[2][128 * 64];
  __shared__ alignas(16) short lB1[2][128 * 64];

  int tid = threadIdx.x;
  int w = tid >> 6, l = tid & 63;
  int wm = w >> 2, wn = w & 3;
  int frow = l & 15, fk = l >> 4;

  // staging: thread covers chunk tid (row r1=tid>>3) and chunk tid+512 (row r1+64)
  int r1 = tid >> 3;
  int kc = ((tid & 7) ^ (r1 & 7)) * 8;          // swizzled global k-chunk (elements)
  int tokA1 = slot_tok[slot0 + r1];
  int tokA2 = slot_tok[slot0 + r1 + 64];
  const __hip_bfloat16* aS1 = xb + (size_t)tokA1 * E_DIM + kc;
  const __hip_bfloat16* aS2 = xb + (size_t)tokA2 * E_DIM + kc;
  const __hip_bfloat16* b0S1 = w0t + ((size_t)e * F_DIM + f0 + r1) * E_DIM + kc;
  const __hip_bfloat16* b0S2 = b0S1 + (size_t)64 * E_DIM;
  const __hip_bfloat16* b1S1 = w1t + ((size_t)e * F_DIM + f0 + r1) * E_DIM + kc;
  const __hip_bfloat16* b1S2 = b1S1 + (size_t)64 * E_DIM;

  f32x4 zero4 = {0.f, 0.f, 0.f, 0.f};
  f32x4 acc0[4][2], acc1[4][2];
#pragma unroll
  for (int mi = 0; mi < 4; mi++)
#pragma unroll
    for (int ni = 0; ni < 2; ni++) { acc0[mi][ni] = zero4; acc1[mi][ni] = zero4; }

  auto stage = [&](int t, int buf) {
    int k0 = t * 64;
    gload_lds16(aS1 + k0,  &lA[buf][w * 512]);
    gload_lds16(aS2 + k0,  &lA[buf][4096 + w * 512]);
    gload_lds16(b0S1 + k0, &lB0[buf][w * 512]);
    gload_lds16(b0S2 + k0, &lB0[buf][4096 + w * 512]);
    gload_lds16(b1S1 + k0, &lB1[buf][w * 512]);
    gload_lds16(b1S2 + k0, &lB1[buf][4096 + w * 512]);
  };

  stage(0, 0);
  __syncthreads();

  const int NT = E_DIM / 64;
  for (int t = 0; t < NT; ++t) {
    int cb = t & 1;
    if (t + 1 < NT) stage(t + 1, cb ^ 1);
    __builtin_amdgcn_s_setprio(1);
#pragma unroll
    for (int ks = 0; ks < 2; ++ks) {
      short8 a[4], b0[2], b1[2];
#pragma unroll
      for (int mi = 0; mi < 4; ++mi) {
        int r = wm * 64 + mi * 16 + frow;
        a[mi] = *(const short8*)&lA[cb][r * 64 + ((ks * 4 + fk) ^ (r & 7)) * 8];
      }
#pragma unroll
      for (int ni = 0; ni < 2; ++ni) {
        int n = wn * 32 + ni * 16 + frow;
        int off = n * 64 + ((ks * 4 + fk) ^ (n & 7)) * 8;
        b0[ni] = *(const short8*)&lB0[cb][off];
        b1[ni] = *(const short8*)&lB1[cb][off];
      }
#pragma unroll
      for (int mi = 0; mi < 4; ++mi)
#pragma unroll
        for (int ni = 0; ni < 2; ++ni) {
          acc0[mi][ni] = __builtin_amdgcn_mfma_f32_16x16x32_bf16(a[mi], b0[ni], acc0[mi][ni], 0, 0, 0);
          acc1[mi][ni] = __builtin_amdgcn_mfma_f32_16x16x32_bf16(a[mi], b1[ni], acc1[mi][ni], 0, 0, 0);
        }
    }
    __builtin_amdgcn_s_setprio(0);
    __syncthreads();
  }

#pragma unroll
  for (int mi = 0; mi < 4; ++mi) {
#pragma unroll
    for (int j = 0; j < 4; ++j) {
      int r = wm * 64 + mi * 16 + fk * 4 + j;
      if (r < rowsv) {
        __hip_bfloat16* hr = h + (size_t)(slot0 + r) * F_DIM + f0 + wn * 32;
#pragma unroll
        for (int ni = 0; ni < 2; ++ni) {
          float v0 = acc0[mi][ni][j];
          float v1 = acc1[mi][ni][j];
          float s = (v0 / (1.f + __expf(-v0))) * v1;
          hr[ni * 16 + frow] = __float2bfloat16(s);
        }
      }
    }
  }
}

// ---------------- GEMM2: parts[slot] = p * (h @ wo) ----------------
__global__ __launch_bounds__(512, 2) void gemm2_kernel(const __hip_bfloat16* __restrict__ h,
                                                       const __hip_bfloat16* __restrict__ wot,
                                                       const int* __restrict__ ctrl,
                                                       const float* __restrict__ slot_prob,
                                                       float* __restrict__ parts) {
  int lin = blockIdx.x;                         // 320 = 8 * 40
  int logical = (lin & 7) * 40 + (lin >> 3);
  int mt = logical % 40;
  int ey = logical / 40;                        // 0..7
  if (mt >= ctrl[24]) return;
  int e = ctrl[32 + mt];
  int slot0 = ctrl[96 + mt];
  int rowsv = ctrl[160 + mt];
  int e0 = ey * 128;

  __shared__ alignas(16) short lA[2][128 * 64];
  __shared__ alignas(16) short lB[2][128 * 64];

  int tid = threadIdx.x;
  int w = tid >> 6, l = tid & 63;
  int wm = w >> 2, wn = w & 3;
  int frow = l & 15, fk = l >> 4;

  int r1 = tid >> 3;
  int kc = ((tid & 7) ^ (r1 & 7)) * 8;
  const __hip_bfloat16* aS1 = h + (size_t)(slot0 + r1) * F_DIM + kc;
  const __hip_bfloat16* aS2 = aS1 + (size_t)64 * F_DIM;
  const __hip_bfloat16* bS1 = wot + ((size_t)e * E_DIM + e0 + r1) * F_DIM + kc;
  const __hip_bfloat16* bS2 = bS1 + (size_t)64 * F_DIM;

  f32x4 zero4 = {0.f, 0.f, 0.f, 0.f};
  f32x4 acc[4][2];
#pragma unroll
  for (int mi = 0; mi < 4; mi++)
#pragma unroll
    for (int ni = 0; ni < 2; ni++) acc[mi][ni] = zero4;

  auto stage = [&](int t, int buf) {
    int k0 = t * 64;
    gload_lds16(aS1 + k0, &lA[buf][w * 512]);
    gload_lds16(aS2 + k0, &lA[buf][4096 + w * 512]);
    gload_lds16(bS1 + k0, &lB[buf][w * 512]);
    gload_lds16(bS2 + k0, &lB[buf][4096 + w * 512]);
  };

  stage(0, 0);
  __syncthreads();

  const int NT = F_DIM / 64;
  for (int t = 0; t < NT; ++t) {
    int cb = t & 1;
    if (t + 1 < NT) stage(t + 1, cb ^ 1);
    __builtin_amdgcn_s_setprio(1);
#pragma unroll
    for (int ks = 0; ks < 2; ++ks) {
      short8 a[4], b[2];
#pragma unroll
      for (int mi = 0; mi < 4; ++mi) {
        int r = wm * 64 + mi * 16 + frow;
        a[mi] = *(const short8*)&lA[cb][r * 64 + ((ks * 4 + fk) ^ (r & 7)) * 8];
      }
#pragma unroll
      for (int ni = 0; ni < 2; ++ni) {
        int n = wn * 32 + ni * 16 + frow;
        b[ni] = *(const short8*)&lB[cb][n * 64 + ((ks * 4 + fk) ^ (n & 7)) * 8];
      }
#pragma unroll
      for (int mi = 0; mi < 4; ++mi)
#pragma unroll
        for (int ni = 0; ni < 2; ++ni)
          acc[mi][ni] = __builtin_amdgcn_mfma_f32_16x16x32_bf16(a[mi], b[ni], acc[mi][ni], 0, 0, 0);
    }
    __builtin_amdgcn_s_setprio(0);
    __syncthreads();
  }

#pragma unroll
  for (int mi = 0; mi < 4; ++mi) {
#pragma unroll
    for (int j = 0; j < 4; ++j) {
      int r = wm * 64 + mi * 16 + fk * 4 + j;
      if (r < rowsv) {
        int slot = slot0 + r;
        float p = slot_prob[slot];
        float* pr = parts + (size_t)slot * E_DIM + e0 + wn * 32;
#pragma unroll
        for (int ni = 0; ni < 2; ++ni)
          pr[ni * 16 + frow] = p * acc[mi][ni][j];
      }
    }
  }
}

// ---------------- combine: out[t] = parts[s1] + parts[s2] ----------------
__global__ __launch_bounds__(256) void combine_kernel(const float* __restrict__ parts,
                                                      const int* __restrict__ inv,
                                                      float* __restrict__ out) {
  int g = blockIdx.x * 256 + threadIdx.x;   // T_TOK*128
  int row = g >> 7, c = (g & 127) * 8;
  int s1 = inv[row * 2], s2 = inv[row * 2 + 1];
  const float4* p1 = (const float4*)(parts + (size_t)s1 * E_DIM + c);
  const float4* p2 = (const float4*)(parts + (size_t)s2 * E_DIM + c);
  float4 a0 = p1[0], a1 = p1[1], b0 = p2[0], b1 = p2[1];
  float4 o0 = {a0.x + b0.x, a0.y + b0.y, a0.z + b0.z, a0.w + b0.w};
  float4 o1 = {a1.x + b1.x, a1.y + b1.y, a1.z + b1.z, a1.w + b1.w};
  float4* op = (float4*)(out + (size_t)row * E_DIM + c);
  op[0] = o0; op[1] = o1;
}

extern "C" void kernel_launch(void* const* d_in, const int* in_sizes, int n_in,
                              void* d_out, int out_size, void* d_ws, size_t ws_size,
                              hipStream_t stream) {
  const float* x  = (const float*)d_in[0];
  const float* gk = (const float*)d_in[1];
  const float* w0 = (const float*)d_in[2];
  const float* w1 = (const float*)d_in[3];
  const float* wo = (const float*)d_in[4];
  float* out = (float*)d_out;
  char* ws = (char*)d_ws;

  const size_t SLOTS = 2 * T_TOK + 128;
  const size_t OFF_XB   = 0;
  const size_t OFF_W0T  = OFF_XB  + (size_t)T_TOK * E_DIM * 2;
  const size_t OFF_W1T  = OFF_W0T + (size_t)N_EXP * E_DIM * F_DIM * 2;
  const size_t OFF_WOT  = OFF_W1T + (size_t)N_EXP * E_DIM * F_DIM * 2;
  const size_t OFF_H    = OFF_WOT + (size_t)N_EXP * F_DIM * E_DIM * 2;
  const size_t OFF_STOK = OFF_H   + SLOTS * F_DIM * 2;
  const size_t OFF_SPRB = OFF_STOK + SLOTS * 4;
  const size_t OFF_TKE  = OFF_SPRB + SLOTS * 4;
  const size_t OFF_TKP  = OFF_TKE + (size_t)2 * T_TOK * 4;
  const size_t OFF_INV  = OFF_TKP + (size_t)2 * T_TOK * 4;
  const size_t OFF_CTRL = OFF_INV + (size_t)2 * T_TOK * 4;
  const size_t NEED     = OFF_CTRL + 1024;
  if (ws_size < NEED) return;

  __hip_bfloat16* xb   = (__hip_bfloat16*)(ws + OFF_XB);
  __hip_bfloat16* w0t  = (__hip_bfloat16*)(ws + OFF_W0T);
  __hip_bfloat16* w1t  = (__hip_bfloat16*)(ws + OFF_W1T);
  __hip_bfloat16* wot  = (__hip_bfloat16*)(ws + OFF_WOT);
  __hip_bfloat16* hbuf = (__hip_bfloat16*)(ws + OFF_H);
  float* parts     = (float*)(ws + OFF_W0T);   // alias: w0t dead after gemm1
  int*   slot_tok  = (int*)(ws + OFF_STOK);
  float* slot_prob = (float*)(ws + OFF_SPRB);
  int*   tk_e      = (int*)(ws + OFF_TKE);
  float* tk_p      = (float*)(ws + OFF_TKP);
  int*   inv       = (int*)(ws + OFF_INV);
  int*   ctrl      = (int*)(ws + OFF_CTRL);

  hipMemsetAsync(ctrl, 0, 1024, stream);
  hipMemsetAsync(slot_tok + 2 * T_TOK, 0, 128 * 4, stream);

  convert_x_kernel<<<(T_TOK * E_DIM) / (256 * 8), 256, 0, stream>>>(x, xb);
  router_kernel<<<T_TOK / 4, 256, 0, stream>>>(x, gk, tk_e, tk_p, ctrl);
  scanperm_kernel<<<1, 256, 0, stream>>>(tk_e, tk_p, ctrl, slot_tok, slot_prob, inv);
  transpose_all_kernel<<<dim3(32, 16, 24), 256, 0, stream>>>(w0, w1, wo, w0t, w1t, wot);
  gemm1_kernel<<<dim3(640), 512, 0, stream>>>(xb, w0t, w1t, ctrl, slot_tok, hbuf);
  gemm2_kernel<<<dim3(320), 512, 0, stream>>>(hbuf, wot, ctrl, slot_prob, parts);
  combine_kernel<<<(T_TOK * 128) / 256, 256, 0, stream>>>(parts, inv, out);
}

// Round 4
// 228.484 us; speedup vs baseline: 1.1536x; 1.0839x over previous
//
#include <hip/hip_runtime.h>
#include <hip/hip_bf16.h>

#define T_TOK 2048
#define E_DIM 1024
#define F_DIM 2048
#define N_EXP 8

typedef __attribute__((ext_vector_type(8))) short short8;
typedef __attribute__((ext_vector_type(4))) float f32x4;

__device__ __forceinline__ short bf2s(__hip_bfloat16 v) {
  union { __hip_bfloat16 b; short s; } u; u.b = v; return u.s;
}

__device__ __forceinline__ void gload_lds16(const void* g, void* l) {
  __builtin_amdgcn_global_load_lds((const __attribute__((address_space(1))) void*)g,
                                   (__attribute__((address_space(3))) void*)l, 16, 0, 0);
}

// ---------------- x fp32 -> bf16 ----------------
__global__ __launch_bounds__(256) void convert_x_kernel(const float* __restrict__ x,
                                                        __hip_bfloat16* __restrict__ xb) {
  size_t i = ((size_t)blockIdx.x * 256 + threadIdx.x) * 8;
  float4 a = *(const float4*)(x + i);
  float4 b = *(const float4*)(x + i + 4);
  short8 o;
  o[0] = bf2s(__float2bfloat16(a.x)); o[1] = bf2s(__float2bfloat16(a.y));
  o[2] = bf2s(__float2bfloat16(a.z)); o[3] = bf2s(__float2bfloat16(a.w));
  o[4] = bf2s(__float2bfloat16(b.x)); o[5] = bf2s(__float2bfloat16(b.y));
  o[6] = bf2s(__float2bfloat16(b.z)); o[7] = bf2s(__float2bfloat16(b.w));
  *(short8*)(xb + i) = o;
}

// ------------- merged transpose+convert: fp32 [R][C] -> bf16 [C][R] -------------
// fp32 LDS tile, stride 65 (65 = 1 mod 32 -> <=2-way banks both directions)
// z 0..7: w0 (R=E,C=F); z 8..15: w1; z 16..23: wo (R=F,C=E)
__global__ __launch_bounds__(256) void transpose_all_kernel(const float* __restrict__ w0,
                                                            const float* __restrict__ w1,
                                                            const float* __restrict__ wo,
                                                            __hip_bfloat16* __restrict__ w0t,
                                                            __hip_bfloat16* __restrict__ w1t,
                                                            __hip_bfloat16* __restrict__ wot) {
  __shared__ float lt[64 * 65];
  int z = blockIdx.z;
  const float* src; __hip_bfloat16* dst;
  int R, C, r0, c0;
  if (z < 16) {
    R = E_DIM; C = F_DIM;
    int e = z & 7;
    src = (z < 8 ? w0 : w1) + (size_t)e * R * C;
    dst = (z < 8 ? w0t : w1t) + (size_t)e * R * C;
    r0 = blockIdx.y * 64; c0 = blockIdx.x * 64;
  } else {
    R = F_DIM; C = E_DIM;
    int e = z - 16;
    src = wo + (size_t)e * R * C;
    dst = wot + (size_t)e * R * C;
    c0 = (blockIdx.x & 15) * 64;
    r0 = (blockIdx.y * 2 + (blockIdx.x >> 4)) * 64;
  }
  int tid = threadIdx.x;
#pragma unroll
  for (int i = 0; i < 4; i++) {
    int chunk = i * 256 + tid;
    int r = chunk >> 4, c4 = (chunk & 15) * 4;
    float4 v = *(const float4*)(src + (size_t)(r0 + r) * C + c0 + c4);
    float* p = &lt[r * 65 + c4];
    p[0] = v.x; p[1] = v.y; p[2] = v.z; p[3] = v.w;
  }
  __syncthreads();
#pragma unroll
  for (int i = 0; i < 2; i++) {
    int chunk = i * 256 + tid;
    int c = chunk >> 3, rr = (chunk & 7) * 8;
    short8 o;
#pragma unroll
    for (int j = 0; j < 8; j++) o[j] = bf2s(__float2bfloat16(lt[(rr + j) * 65 + c]));
    *(short8*)(dst + (size_t)(c0 + c) * R + r0 + rr) = o;
  }
}

// ---------------- router: fp64 logits, top-2, softmax ----------------
__global__ __launch_bounds__(256) void router_kernel(const float* __restrict__ x,
                                                     const float* __restrict__ gk,
                                                     int* __restrict__ tk_e,
                                                     float* __restrict__ tk_p,
                                                     int* __restrict__ counts) {
  int w = threadIdx.x >> 6, l = threadIdx.x & 63;
  int t = blockIdx.x * 4 + w;
  const float* xr = x + (size_t)t * E_DIM;
  double acc[N_EXP];
#pragma unroll
  for (int n = 0; n < N_EXP; n++) acc[n] = 0.0;
  for (int j = 0; j < 16; j++) {
    int i = j * 64 + l;
    double xv = (double)xr[i];
    const float* g = gk + (size_t)i * N_EXP;
#pragma unroll
    for (int n = 0; n < N_EXP; n++) acc[n] += xv * (double)g[n];
  }
#pragma unroll
  for (int off = 32; off > 0; off >>= 1) {
#pragma unroll
    for (int n = 0; n < N_EXP; n++) acc[n] += __shfl_down(acc[n], off);
  }
  if (l == 0) {
    int e1 = 0; double v1 = acc[0];
    for (int n = 1; n < N_EXP; n++) if (acc[n] > v1) { v1 = acc[n]; e1 = n; }
    int e2 = -1; double v2 = -1e300;
    for (int n = 0; n < N_EXP; n++) if (n != e1 && acc[n] > v2) { v2 = acc[n]; e2 = n; }
    float ex = __expf((float)(v2 - v1));     // <= 1
    float p1 = 1.f / (1.f + ex);
    float p2 = ex / (1.f + ex);
    tk_e[t * 2 + 0] = e1; tk_p[t * 2 + 0] = p1;
    tk_e[t * 2 + 1] = e2; tk_p[t * 2 + 1] = p2;
    atomicAdd(&counts[e1], 1);
    atomicAdd(&counts[e2], 1);
  }
}

// ---------------- scan + permute, single block ----------------
__global__ __launch_bounds__(256) void scanperm_kernel(const int* __restrict__ tk_e,
                                                       const float* __restrict__ tk_p,
                                                       int* __restrict__ ctrl,
                                                       int* __restrict__ slot_tok,
                                                       float* __restrict__ slot_prob,
                                                       int* __restrict__ inv) {
  __shared__ int offs[8], cur[8];
  int tid = threadIdx.x;
  if (tid == 0) {
    int off = 0, idx = 0;
    for (int e = 0; e < N_EXP; e++) {
      offs[e] = off; cur[e] = 0;
      int c = ctrl[e];
      for (int m0 = 0; m0 < c; m0 += 128) {
        ctrl[32 + idx] = e;
        ctrl[96 + idx] = off + m0;
        ctrl[160 + idx] = (c - m0 < 128) ? (c - m0) : 128;
        idx++;
      }
      off += c;
    }
    ctrl[24] = idx;
  }
  __syncthreads();
  for (int g = tid; g < 2 * T_TOK; g += 256) {
    int e = tk_e[g];
    float p = tk_p[g];
    int pos = atomicAdd(&cur[e], 1);
    int slot = offs[e] + pos;
    slot_tok[slot] = g >> 1;
    slot_prob[slot] = p;
    inv[g] = slot;
  }
}

// ---------------- GEMM1: h = silu(X@w0)*(X@w1) ----------------
// 512 thr (8 waves, 2m x 4n), BM=128 BN=128 BK=64, single-buffered LDS (48KB),
// 2 barriers/K-step, >=2 blocks/CU for cross-block drain overlap
__global__ __launch_bounds__(512, 4) void gemm1_kernel(const __hip_bfloat16* __restrict__ xb,
                                                       const __hip_bfloat16* __restrict__ w0t,
                                                       const __hip_bfloat16* __restrict__ w1t,
                                                       const int* __restrict__ ctrl,
                                                       const int* __restrict__ slot_tok,
                                                       __hip_bfloat16* __restrict__ h) {
  int lin = blockIdx.x;                         // 640 = 8 * 80
  int logical = (lin & 7) * 80 + (lin >> 3);    // XCD-chunked: same fy stays on one XCD
  int mt = logical % 40;
  int fy = logical / 40;                        // 0..15
  if (mt >= ctrl[24]) return;
  int e = ctrl[32 + mt];
  int slot0 = ctrl[96 + mt];
  int rowsv = ctrl[160 + mt];
  int f0 = fy * 128;

  __shared__ alignas(16) short lA[128 * 64];
  __shared__ alignas(16) short lB0[128 * 64];
  __shared__ alignas(16) short lB1[128 * 64];

  int tid = threadIdx.x;
  int w = tid >> 6, l = tid & 63;
  int wm = w >> 2, wn = w & 3;
  int frow = l & 15, fk = l >> 4;

  int r1 = tid >> 3;
  int kc = ((tid & 7) ^ (r1 & 7)) * 8;          // swizzled global k-chunk (elements)
  int tokA1 = slot_tok[slot0 + r1];
  int tokA2 = slot_tok[slot0 + r1 + 64];
  const __hip_bfloat16* aS1 = xb + (size_t)tokA1 * E_DIM + kc;
  const __hip_bfloat16* aS2 = xb + (size_t)tokA2 * E_DIM + kc;
  const __hip_bfloat16* b0S1 = w0t + ((size_t)e * F_DIM + f0 + r1) * E_DIM + kc;
  const __hip_bfloat16* b0S2 = b0S1 + (size_t)64 * E_DIM;
  const __hip_bfloat16* b1S1 = w1t + ((size_t)e * F_DIM + f0 + r1) * E_DIM + kc;
  const __hip_bfloat16* b1S2 = b1S1 + (size_t)64 * E_DIM;

  f32x4 zero4 = {0.f, 0.f, 0.f, 0.f};
  f32x4 acc0[4][2], acc1[4][2];
#pragma unroll
  for (int mi = 0; mi < 4; mi++)
#pragma unroll
    for (int ni = 0; ni < 2; ni++) { acc0[mi][ni] = zero4; acc1[mi][ni] = zero4; }

  auto stage = [&](int t) {
    int k0 = t * 64;
    gload_lds16(aS1 + k0,  &lA[w * 512]);
    gload_lds16(aS2 + k0,  &lA[4096 + w * 512]);
    gload_lds16(b0S1 + k0, &lB0[w * 512]);
    gload_lds16(b0S2 + k0, &lB0[4096 + w * 512]);
    gload_lds16(b1S1 + k0, &lB1[w * 512]);
    gload_lds16(b1S2 + k0, &lB1[4096 + w * 512]);
  };

  const int NT = E_DIM / 64;
  for (int t = 0; t < NT; ++t) {
    if (t) __syncthreads();
    stage(t);
    __syncthreads();
    __builtin_amdgcn_s_setprio(1);
#pragma unroll
    for (int ks = 0; ks < 2; ++ks) {
      short8 a[4], b0[2], b1[2];
#pragma unroll
      for (int mi = 0; mi < 4; ++mi) {
        int r = wm * 64 + mi * 16 + frow;
        a[mi] = *(const short8*)&lA[r * 64 + ((ks * 4 + fk) ^ (r & 7)) * 8];
      }
#pragma unroll
      for (int ni = 0; ni < 2; ++ni) {
        int n = wn * 32 + ni * 16 + frow;
        int off = n * 64 + ((ks * 4 + fk) ^ (n & 7)) * 8;
        b0[ni] = *(const short8*)&lB0[off];
        b1[ni] = *(const short8*)&lB1[off];
      }
#pragma unroll
      for (int mi = 0; mi < 4; ++mi)
#pragma unroll
        for (int ni = 0; ni < 2; ++ni) {
          acc0[mi][ni] = __builtin_amdgcn_mfma_f32_16x16x32_bf16(a[mi], b0[ni], acc0[mi][ni], 0, 0, 0);
          acc1[mi][ni] = __builtin_amdgcn_mfma_f32_16x16x32_bf16(a[mi], b1[ni], acc1[mi][ni], 0, 0, 0);
        }
    }
    __builtin_amdgcn_s_setprio(0);
  }

#pragma unroll
  for (int mi = 0; mi < 4; ++mi) {
#pragma unroll
    for (int j = 0; j < 4; ++j) {
      int r = wm * 64 + mi * 16 + fk * 4 + j;
      if (r < rowsv) {
        __hip_bfloat16* hr = h + (size_t)(slot0 + r) * F_DIM + f0 + wn * 32;
#pragma unroll
        for (int ni = 0; ni < 2; ++ni) {
          float v0 = acc0[mi][ni][j];
          float v1 = acc1[mi][ni][j];
          float s = (v0 / (1.f + __expf(-v0))) * v1;
          hr[ni * 16 + frow] = __float2bfloat16(s);
        }
      }
    }
  }
}

// ---------------- GEMM2: parts[slot] = p * (h @ wo) ----------------
__global__ __launch_bounds__(512, 4) void gemm2_kernel(const __hip_bfloat16* __restrict__ h,
                                                       const __hip_bfloat16* __restrict__ wot,
                                                       const int* __restrict__ ctrl,
                                                       const float* __restrict__ slot_prob,
                                                       float* __restrict__ parts) {
  int lin = blockIdx.x;                         // 320 = 8 * 40
  int logical = (lin & 7) * 40 + (lin >> 3);
  int mt = logical % 40;
  int ey = logical / 40;                        // 0..7
  if (mt >= ctrl[24]) return;
  int e = ctrl[32 + mt];
  int slot0 = ctrl[96 + mt];
  int rowsv = ctrl[160 + mt];
  int e0 = ey * 128;

  __shared__ alignas(16) short lA[128 * 64];
  __shared__ alignas(16) short lB[128 * 64];

  int tid = threadIdx.x;
  int w = tid >> 6, l = tid & 63;
  int wm = w >> 2, wn = w & 3;
  int frow = l & 15, fk = l >> 4;

  int r1 = tid >> 3;
  int kc = ((tid & 7) ^ (r1 & 7)) * 8;
  const __hip_bfloat16* aS1 = h + (size_t)(slot0 + r1) * F_DIM + kc;
  const __hip_bfloat16* aS2 = aS1 + (size_t)64 * F_DIM;
  const __hip_bfloat16* bS1 = wot + ((size_t)e * E_DIM + e0 + r1) * F_DIM + kc;
  const __hip_bfloat16* bS2 = bS1 + (size_t)64 * F_DIM;

  f32x4 zero4 = {0.f, 0.f, 0.f, 0.f};
  f32x4 acc[4][2];
#pragma unroll
  for (int mi = 0; mi < 4; mi++)
#pragma unroll
    for (int ni = 0; ni < 2; ni++) acc[mi][ni] = zero4;

  auto stage = [&](int t) {
    int k0 = t * 64;
    gload_lds16(aS1 + k0, &lA[w * 512]);
    gload_lds16(aS2 + k0, &lA[4096 + w * 512]);
    gload_lds16(bS1 + k0, &lB[w * 512]);
    gload_lds16(bS2 + k0, &lB[4096 + w * 512]);
  };

  const int NT = F_DIM / 64;
  for (int t = 0; t < NT; ++t) {
    if (t) __syncthreads();
    stage(t);
    __syncthreads();
    __builtin_amdgcn_s_setprio(1);
#pragma unroll
    for (int ks = 0; ks < 2; ++ks) {
      short8 a[4], b[2];
#pragma unroll
      for (int mi = 0; mi < 4; ++mi) {
        int r = wm * 64 + mi * 16 + frow;
        a[mi] = *(const short8*)&lA[r * 64 + ((ks * 4 + fk) ^ (r & 7)) * 8];
      }
#pragma unroll
      for (int ni = 0; ni < 2; ++ni) {
        int n = wn * 32 + ni * 16 + frow;
        b[ni] = *(const short8*)&lB[n * 64 + ((ks * 4 + fk) ^ (n & 7)) * 8];
      }
#pragma unroll
      for (int mi = 0; mi < 4; ++mi)
#pragma unroll
        for (int ni = 0; ni < 2; ++ni)
          acc[mi][ni] = __builtin_amdgcn_mfma_f32_16x16x32_bf16(a[mi], b[ni], acc[mi][ni], 0, 0, 0);
    }
    __builtin_amdgcn_s_setprio(0);
  }

#pragma unroll
  for (int mi = 0; mi < 4; ++mi) {
#pragma unroll
    for (int j = 0; j < 4; ++j) {
      int r = wm * 64 + mi * 16 + fk * 4 + j;
      if (r < rowsv) {
        int slot = slot0 + r;
        float p = slot_prob[slot];
        float* pr = parts + (size_t)slot * E_DIM + e0 + wn * 32;
#pragma unroll
        for (int ni = 0; ni < 2; ++ni)
          pr[ni * 16 + frow] = p * acc[mi][ni][j];
      }
    }
  }
}

// ---------------- combine: out[t] = parts[s1] + parts[s2] ----------------
__global__ __launch_bounds__(256) void combine_kernel(const float* __restrict__ parts,
                                                      const int* __restrict__ inv,
                                                      float* __restrict__ out) {
  int g = blockIdx.x * 256 + threadIdx.x;   // T_TOK*128
  int row = g >> 7, c = (g & 127) * 8;
  int s1 = inv[row * 2], s2 = inv[row * 2 + 1];
  const float4* p1 = (const float4*)(parts + (size_t)s1 * E_DIM + c);
  const float4* p2 = (const float4*)(parts + (size_t)s2 * E_DIM + c);
  float4 a0 = p1[0], a1 = p1[1], b0 = p2[0], b1 = p2[1];
  float4 o0 = {a0.x + b0.x, a0.y + b0.y, a0.z + b0.z, a0.w + b0.w};
  float4 o1 = {a1.x + b1.x, a1.y + b1.y, a1.z + b1.z, a1.w + b1.w};
  float4* op = (float4*)(out + (size_t)row * E_DIM + c);
  op[0] = o0; op[1] = o1;
}

extern "C" void kernel_launch(void* const* d_in, const int* in_sizes, int n_in,
                              void* d_out, int out_size, void* d_ws, size_t ws_size,
                              hipStream_t stream) {
  const float* x  = (const float*)d_in[0];
  const float* gk = (const float*)d_in[1];
  const float* w0 = (const float*)d_in[2];
  const float* w1 = (const float*)d_in[3];
  const float* wo = (const float*)d_in[4];
  float* out = (float*)d_out;
  char* ws = (char*)d_ws;

  const size_t SLOTS = 2 * T_TOK + 128;
  const size_t OFF_XB   = 0;
  const size_t OFF_W0T  = OFF_XB  + (size_t)T_TOK * E_DIM * 2;
  const size_t OFF_W1T  = OFF_W0T + (size_t)N_EXP * E_DIM * F_DIM * 2;
  const size_t OFF_WOT  = OFF_W1T + (size_t)N_EXP * E_DIM * F_DIM * 2;
  const size_t OFF_H    = OFF_WOT + (size_t)N_EXP * F_DIM * E_DIM * 2;
  const size_t OFF_STOK = OFF_H   + SLOTS * F_DIM * 2;
  const size_t OFF_SPRB = OFF_STOK + SLOTS * 4;
  const size_t OFF_TKE  = OFF_SPRB + SLOTS * 4;
  const size_t OFF_TKP  = OFF_TKE + (size_t)2 * T_TOK * 4;
  const size_t OFF_INV  = OFF_TKP + (size_t)2 * T_TOK * 4;
  const size_t OFF_CTRL = OFF_INV + (size_t)2 * T_TOK * 4;
  const size_t NEED     = OFF_CTRL + 1024;
  if (ws_size < NEED) return;

  __hip_bfloat16* xb   = (__hip_bfloat16*)(ws + OFF_XB);
  __hip_bfloat16* w0t  = (__hip_bfloat16*)(ws + OFF_W0T);
  __hip_bfloat16* w1t  = (__hip_bfloat16*)(ws + OFF_W1T);
  __hip_bfloat16* wot  = (__hip_bfloat16*)(ws + OFF_WOT);
  __hip_bfloat16* hbuf = (__hip_bfloat16*)(ws + OFF_H);
  float* parts     = (float*)(ws + OFF_W0T);   // alias: w0t dead after gemm1
  int*   slot_tok  = (int*)(ws + OFF_STOK);
  float* slot_prob = (float*)(ws + OFF_SPRB);
  int*   tk_e      = (int*)(ws + OFF_TKE);
  float* tk_p      = (float*)(ws + OFF_TKP);
  int*   inv       = (int*)(ws + OFF_INV);
  int*   ctrl      = (int*)(ws + OFF_CTRL);

  hipMemsetAsync(ctrl, 0, 1024, stream);
  hipMemsetAsync(slot_tok + 2 * T_TOK, 0, 128 * 4, stream);

  transpose_all_kernel<<<dim3(32, 16, 24), 256, 0, stream>>>(w0, w1, wo, w0t, w1t, wot);
  convert_x_kernel<<<(T_TOK * E_DIM) / (256 * 8), 256, 0, stream>>>(x, xb);
  router_kernel<<<T_TOK / 4, 256, 0, stream>>>(x, gk, tk_e, tk_p, ctrl);
  scanperm_kernel<<<1, 256, 0, stream>>>(tk_e, tk_p, ctrl, slot_tok, slot_prob, inv);
  gemm1_kernel<<<dim3(640), 512, 0, stream>>>(xb, w0t, w1t, ctrl, slot_tok, hbuf);
  gemm2_kernel<<<dim3(320), 512, 0, stream>>>(hbuf, wot, ctrl, slot_prob, parts);
  combine_kernel<<<(T_TOK * 128) / 256, 256, 0, stream>>>(parts, inv, out);
}

// Round 5
// 221.595 us; speedup vs baseline: 1.1894x; 1.0311x over previous
//
#include <hip/hip_runtime.h>
#include <hip/hip_bf16.h>

#define T_TOK 2048
#define E_DIM 1024
#define F_DIM 2048
#define N_EXP 8

typedef __attribute__((ext_vector_type(8))) short short8;
typedef __attribute__((ext_vector_type(4))) float f32x4;

// full-entropy 3-bit swizzle for B-tile (used on write and read identically)
#define SWZB(f) (((f) ^ ((f) >> 3)) & 7)

__device__ __forceinline__ short bf2s(__hip_bfloat16 v) {
  union { __hip_bfloat16 b; short s; } u; u.b = v; return u.s;
}

__device__ __forceinline__ void gload_lds16(const void* g, void* l) {
  __builtin_amdgcn_global_load_lds((const __attribute__((address_space(1))) void*)g,
                                   (__attribute__((address_space(3))) void*)l, 16, 0, 0);
}

// ---------------- x fp32 -> bf16 ----------------
__global__ __launch_bounds__(256) void convert_x_kernel(const float* __restrict__ x,
                                                        __hip_bfloat16* __restrict__ xb) {
  size_t i = ((size_t)blockIdx.x * 256 + threadIdx.x) * 8;
  float4 a = *(const float4*)(x + i);
  float4 b = *(const float4*)(x + i + 4);
  short8 o;
  o[0] = bf2s(__float2bfloat16(a.x)); o[1] = bf2s(__float2bfloat16(a.y));
  o[2] = bf2s(__float2bfloat16(a.z)); o[3] = bf2s(__float2bfloat16(a.w));
  o[4] = bf2s(__float2bfloat16(b.x)); o[5] = bf2s(__float2bfloat16(b.y));
  o[6] = bf2s(__float2bfloat16(b.z)); o[7] = bf2s(__float2bfloat16(b.w));
  *(short8*)(xb + i) = o;
}

// ---------------- router: fp64 logits, top-2, softmax ----------------
__global__ __launch_bounds__(256) void router_kernel(const float* __restrict__ x,
                                                     const float* __restrict__ gk,
                                                     int* __restrict__ tk_e,
                                                     float* __restrict__ tk_p,
                                                     int* __restrict__ counts) {
  int w = threadIdx.x >> 6, l = threadIdx.x & 63;
  int t = blockIdx.x * 4 + w;
  const float* xr = x + (size_t)t * E_DIM;
  double acc[N_EXP];
#pragma unroll
  for (int n = 0; n < N_EXP; n++) acc[n] = 0.0;
  for (int j = 0; j < 16; j++) {
    int i = j * 64 + l;
    double xv = (double)xr[i];
    const float* g = gk + (size_t)i * N_EXP;
#pragma unroll
    for (int n = 0; n < N_EXP; n++) acc[n] += xv * (double)g[n];
  }
#pragma unroll
  for (int off = 32; off > 0; off >>= 1) {
#pragma unroll
    for (int n = 0; n < N_EXP; n++) acc[n] += __shfl_down(acc[n], off);
  }
  if (l == 0) {
    int e1 = 0; double v1 = acc[0];
    for (int n = 1; n < N_EXP; n++) if (acc[n] > v1) { v1 = acc[n]; e1 = n; }
    int e2 = -1; double v2 = -1e300;
    for (int n = 0; n < N_EXP; n++) if (n != e1 && acc[n] > v2) { v2 = acc[n]; e2 = n; }
    float ex = __expf((float)(v2 - v1));     // <= 1
    float p1 = 1.f / (1.f + ex);
    float p2 = ex / (1.f + ex);
    tk_e[t * 2 + 0] = e1; tk_p[t * 2 + 0] = p1;
    tk_e[t * 2 + 1] = e2; tk_p[t * 2 + 1] = p2;
    atomicAdd(&counts[e1], 1);
    atomicAdd(&counts[e2], 1);
  }
}

// ---------------- scan + permute, single block ----------------
__global__ __launch_bounds__(256) void scanperm_kernel(const int* __restrict__ tk_e,
                                                       const float* __restrict__ tk_p,
                                                       int* __restrict__ ctrl,
                                                       int* __restrict__ slot_tok,
                                                       float* __restrict__ slot_prob,
                                                       int* __restrict__ inv) {
  __shared__ int offs[8], cur[8];
  int tid = threadIdx.x;
  if (tid == 0) {
    int off = 0, idx = 0;
    for (int e = 0; e < N_EXP; e++) {
      offs[e] = off; cur[e] = 0;
      int c = ctrl[e];
      for (int m0 = 0; m0 < c; m0 += 128) {
        ctrl[32 + idx] = e;
        ctrl[96 + idx] = off + m0;
        ctrl[160 + idx] = (c - m0 < 128) ? (c - m0) : 128;
        idx++;
      }
      off += c;
    }
    ctrl[24] = idx;
  }
  __syncthreads();
  for (int g = tid; g < 2 * T_TOK; g += 256) {
    int e = tk_e[g];
    float p = tk_p[g];
    int pos = atomicAdd(&cur[e], 1);
    int slot = offs[e] + pos;
    slot_tok[slot] = g >> 1;
    slot_prob[slot] = p;
    inv[g] = slot;
  }
}

// ---------------- GEMM1: h = silu(X@w0)*(X@w1), fp32 B fused convert+transpose staging ----------------
// 512 thr (8 waves, 2m x 4n), BM=128 BN=128 BK=64, single-buffered LDS (48KB), 2 barriers/K-step
__global__ __launch_bounds__(512, 4) void gemm1_kernel(const __hip_bfloat16* __restrict__ xb,
                                                       const float* __restrict__ w0,
                                                       const float* __restrict__ w1,
                                                       const int* __restrict__ ctrl,
                                                       const int* __restrict__ slot_tok,
                                                       __hip_bfloat16* __restrict__ h) {
  int lin = blockIdx.x;                         // 640 = 8 * 80
  int logical = (lin & 7) * 80 + (lin >> 3);    // XCD-chunked: same fy stays on one XCD
  int mt = logical % 40;
  int fy = logical / 40;                        // 0..15
  if (mt >= ctrl[24]) return;
  int e = ctrl[32 + mt];
  int slot0 = ctrl[96 + mt];
  int rowsv = ctrl[160 + mt];
  int f0 = fy * 128;

  __shared__ alignas(16) short lA[128 * 64];
  __shared__ alignas(16) short lB0[128 * 64];
  __shared__ alignas(16) short lB1[128 * 64];

  int tid = threadIdx.x;
  int w = tid >> 6, l = tid & 63;
  int wm = w >> 2, wn = w & 3;
  int frow = l & 15, fk = l >> 4;

  // ---- A staging (bf16 global_load_lds, pre-swizzled source; proven 0-conflict) ----
  int r1 = tid >> 3;
  int kcA = ((tid & 7) ^ (r1 & 7)) * 8;
  int tokA1 = slot_tok[slot0 + r1];
  int tokA2 = slot_tok[slot0 + r1 + 64];
  const __hip_bfloat16* aS1 = xb + (size_t)tokA1 * E_DIM + kcA;
  const __hip_bfloat16* aS2 = xb + (size_t)tokA2 * E_DIM + kcA;

  // ---- B staging (fp32 rows [k][f] -> cvt -> transposed b64 writes into [f][k]) ----
  int uf = tid & 31, uk = tid >> 5;             // f_base = uf*4; k rows uk*4..uk*4+3
  const float* b0s = w0 + ((size_t)e * E_DIM + uk * 4) * F_DIM + f0 + uf * 4;
  const float* b1s = w1 + ((size_t)e * E_DIM + uk * 4) * F_DIM + f0 + uf * 4;
  // per-j LDS element offsets (k-pack of 4 at column group uk)
  int elB[4];
#pragma unroll
  for (int j = 0; j < 4; ++j) {
    int f = uf * 4 + j;
    elB[j] = f * 64 + (((uk >> 1) ^ SWZB(f)) & 7) * 8 + (uk & 1) * 4;
  }

  f32x4 zero4 = {0.f, 0.f, 0.f, 0.f};
  f32x4 acc0[4][2], acc1[4][2];
#pragma unroll
  for (int mi = 0; mi < 4; mi++)
#pragma unroll
    for (int ni = 0; ni < 2; ni++) { acc0[mi][ni] = zero4; acc1[mi][ni] = zero4; }

  const int NT = E_DIM / 64;
  for (int t = 0; t < NT; ++t) {
    if (t) __syncthreads();
    int k0 = t * 64;
    // A: async direct-to-LDS
    gload_lds16(aS1 + k0, &lA[w * 512]);
    gload_lds16(aS2 + k0, &lA[4096 + w * 512]);
    // B0: load 4 fp32 rows, pack per-f, transposed write
    {
      float4 r[4];
#pragma unroll
      for (int rr = 0; rr < 4; ++rr)
        r[rr] = *(const float4*)(b0s + (size_t)(k0 + rr) * F_DIM);
#pragma unroll
      for (int j = 0; j < 4; ++j) {
        short4 q;
        q.x = bf2s(__float2bfloat16(((const float*)&r[0])[j]));
        q.y = bf2s(__float2bfloat16(((const float*)&r[1])[j]));
        q.z = bf2s(__float2bfloat16(((const float*)&r[2])[j]));
        q.w = bf2s(__float2bfloat16(((const float*)&r[3])[j]));
        *(short4*)&lB0[elB[j]] = q;
      }
    }
    // B1
    {
      float4 r[4];
#pragma unroll
      for (int rr = 0; rr < 4; ++rr)
        r[rr] = *(const float4*)(b1s + (size_t)(k0 + rr) * F_DIM);
#pragma unroll
      for (int j = 0; j < 4; ++j) {
        short4 q;
        q.x = bf2s(__float2bfloat16(((const float*)&r[0])[j]));
        q.y = bf2s(__float2bfloat16(((const float*)&r[1])[j]));
        q.z = bf2s(__float2bfloat16(((const float*)&r[2])[j]));
        q.w = bf2s(__float2bfloat16(((const float*)&r[3])[j]));
        *(short4*)&lB1[elB[j]] = q;
      }
    }
    __syncthreads();
    __builtin_amdgcn_s_setprio(1);
#pragma unroll
    for (int ks = 0; ks < 2; ++ks) {
      short8 a[4], b0[2], b1[2];
#pragma unroll
      for (int mi = 0; mi < 4; ++mi) {
        int r = wm * 64 + mi * 16 + frow;
        a[mi] = *(const short8*)&lA[r * 64 + ((ks * 4 + fk) ^ (r & 7)) * 8];
      }
#pragma unroll
      for (int ni = 0; ni < 2; ++ni) {
        int n = wn * 32 + ni * 16 + frow;
        int off = n * 64 + (((ks * 4 + fk) ^ SWZB(n)) & 7) * 8;
        b0[ni] = *(const short8*)&lB0[off];
        b1[ni] = *(const short8*)&lB1[off];
      }
#pragma unroll
      for (int mi = 0; mi < 4; ++mi)
#pragma unroll
        for (int ni = 0; ni < 2; ++ni) {
          acc0[mi][ni] = __builtin_amdgcn_mfma_f32_16x16x32_bf16(a[mi], b0[ni], acc0[mi][ni], 0, 0, 0);
          acc1[mi][ni] = __builtin_amdgcn_mfma_f32_16x16x32_bf16(a[mi], b1[ni], acc1[mi][ni], 0, 0, 0);
        }
    }
    __builtin_amdgcn_s_setprio(0);
  }

#pragma unroll
  for (int mi = 0; mi < 4; ++mi) {
#pragma unroll
    for (int j = 0; j < 4; ++j) {
      int r = wm * 64 + mi * 16 + fk * 4 + j;
      if (r < rowsv) {
        __hip_bfloat16* hr = h + (size_t)(slot0 + r) * F_DIM + f0 + wn * 32;
#pragma unroll
        for (int ni = 0; ni < 2; ++ni) {
          float v0 = acc0[mi][ni][j];
          float v1 = acc1[mi][ni][j];
          float s = (v0 / (1.f + __expf(-v0))) * v1;
          hr[ni * 16 + frow] = __float2bfloat16(s);
        }
      }
    }
  }
}

// ---------------- GEMM2: parts[slot] = p * (h @ wo), fp32 B fused staging ----------------
__global__ __launch_bounds__(512, 4) void gemm2_kernel(const __hip_bfloat16* __restrict__ h,
                                                       const float* __restrict__ wo,
                                                       const int* __restrict__ ctrl,
                                                       const float* __restrict__ slot_prob,
                                                       float* __restrict__ parts) {
  int lin = blockIdx.x;                         // 320 = 8 * 40
  int logical = (lin & 7) * 40 + (lin >> 3);
  int mt = logical % 40;
  int ey = logical / 40;                        // 0..7
  if (mt >= ctrl[24]) return;
  int e = ctrl[32 + mt];
  int slot0 = ctrl[96 + mt];
  int rowsv = ctrl[160 + mt];
  int e0 = ey * 128;

  __shared__ alignas(16) short lA[128 * 64];
  __shared__ alignas(16) short lB[128 * 64];

  int tid = threadIdx.x;
  int w = tid >> 6, l = tid & 63;
  int wm = w >> 2, wn = w & 3;
  int frow = l & 15, fk = l >> 4;

  int r1 = tid >> 3;
  int kcA = ((tid & 7) ^ (r1 & 7)) * 8;
  const __hip_bfloat16* aS1 = h + (size_t)(slot0 + r1) * F_DIM + kcA;
  const __hip_bfloat16* aS2 = aS1 + (size_t)64 * F_DIM;

  int ue = tid & 31, uk = tid >> 5;             // e_base = ue*4; f rows uk*4..+3
  const float* bs = wo + ((size_t)e * F_DIM + uk * 4) * E_DIM + e0 + ue * 4;
  int elB[4];
#pragma unroll
  for (int j = 0; j < 4; ++j) {
    int f = ue * 4 + j;
    elB[j] = f * 64 + (((uk >> 1) ^ SWZB(f)) & 7) * 8 + (uk & 1) * 4;
  }

  f32x4 zero4 = {0.f, 0.f, 0.f, 0.f};
  f32x4 acc[4][2];
#pragma unroll
  for (int mi = 0; mi < 4; mi++)
#pragma unroll
    for (int ni = 0; ni < 2; ni++) acc[mi][ni] = zero4;

  const int NT = F_DIM / 64;
  for (int t = 0; t < NT; ++t) {
    if (t) __syncthreads();
    int k0 = t * 64;
    gload_lds16(aS1 + k0, &lA[w * 512]);
    gload_lds16(aS2 + k0, &lA[4096 + w * 512]);
    {
      float4 r[4];
#pragma unroll
      for (int rr = 0; rr < 4; ++rr)
        r[rr] = *(const float4*)(bs + (size_t)(k0 + rr) * E_DIM);
#pragma unroll
      for (int j = 0; j < 4; ++j) {
        short4 q;
        q.x = bf2s(__float2bfloat16(((const float*)&r[0])[j]));
        q.y = bf2s(__float2bfloat16(((const float*)&r[1])[j]));
        q.z = bf2s(__float2bfloat16(((const float*)&r[2])[j]));
        q.w = bf2s(__float2bfloat16(((const float*)&r[3])[j]));
        *(short4*)&lB[elB[j]] = q;
      }
    }
    __syncthreads();
    __builtin_amdgcn_s_setprio(1);
#pragma unroll
    for (int ks = 0; ks < 2; ++ks) {
      short8 a[4], b[2];
#pragma unroll
      for (int mi = 0; mi < 4; ++mi) {
        int r = wm * 64 + mi * 16 + frow;
        a[mi] = *(const short8*)&lA[r * 64 + ((ks * 4 + fk) ^ (r & 7)) * 8];
      }
#pragma unroll
      for (int ni = 0; ni < 2; ++ni) {
        int n = wn * 32 + ni * 16 + frow;
        b[ni] = *(const short8*)&lB[n * 64 + (((ks * 4 + fk) ^ SWZB(n)) & 7) * 8];
      }
#pragma unroll
      for (int mi = 0; mi < 4; ++mi)
#pragma unroll
        for (int ni = 0; ni < 2; ++ni)
          acc[mi][ni] = __builtin_amdgcn_mfma_f32_16x16x32_bf16(a[mi], b[ni], acc[mi][ni], 0, 0, 0);
    }
    __builtin_amdgcn_s_setprio(0);
  }

#pragma unroll
  for (int mi = 0; mi < 4; ++mi) {
#pragma unroll
    for (int j = 0; j < 4; ++j) {
      int r = wm * 64 + mi * 16 + fk * 4 + j;
      if (r < rowsv) {
        int slot = slot0 + r;
        float p = slot_prob[slot];
        float* pr = parts + (size_t)slot * E_DIM + e0 + wn * 32;
#pragma unroll
        for (int ni = 0; ni < 2; ++ni)
          pr[ni * 16 + frow] = p * acc[mi][ni][j];
      }
    }
  }
}

// ---------------- combine: out[t] = parts[s1] + parts[s2] ----------------
__global__ __launch_bounds__(256) void combine_kernel(const float* __restrict__ parts,
                                                      const int* __restrict__ inv,
                                                      float* __restrict__ out) {
  int g = blockIdx.x * 256 + threadIdx.x;   // T_TOK*128
  int row = g >> 7, c = (g & 127) * 8;
  int s1 = inv[row * 2], s2 = inv[row * 2 + 1];
  const float4* p1 = (const float4*)(parts + (size_t)s1 * E_DIM + c);
  const float4* p2 = (const float4*)(parts + (size_t)s2 * E_DIM + c);
  float4 a0 = p1[0], a1 = p1[1], b0 = p2[0], b1 = p2[1];
  float4 o0 = {a0.x + b0.x, a0.y + b0.y, a0.z + b0.z, a0.w + b0.w};
  float4 o1 = {a1.x + b1.x, a1.y + b1.y, a1.z + b1.z, a1.w + b1.w};
  float4* op = (float4*)(out + (size_t)row * E_DIM + c);
  op[0] = o0; op[1] = o1;
}

extern "C" void kernel_launch(void* const* d_in, const int* in_sizes, int n_in,
                              void* d_out, int out_size, void* d_ws, size_t ws_size,
                              hipStream_t stream) {
  const float* x  = (const float*)d_in[0];
  const float* gk = (const float*)d_in[1];
  const float* w0 = (const float*)d_in[2];
  const float* w1 = (const float*)d_in[3];
  const float* wo = (const float*)d_in[4];
  float* out = (float*)d_out;
  char* ws = (char*)d_ws;

  const size_t SLOTS = 2 * T_TOK + 128;
  const size_t OFF_XB   = 0;
  const size_t OFF_H    = OFF_XB + (size_t)T_TOK * E_DIM * 2;
  const size_t OFF_PART = OFF_H + SLOTS * F_DIM * 2;
  const size_t OFF_STOK = OFF_PART + SLOTS * E_DIM * 4;
  const size_t OFF_SPRB = OFF_STOK + SLOTS * 4;
  const size_t OFF_TKE  = OFF_SPRB + SLOTS * 4;
  const size_t OFF_TKP  = OFF_TKE + (size_t)2 * T_TOK * 4;
  const size_t OFF_INV  = OFF_TKP + (size_t)2 * T_TOK * 4;
  const size_t OFF_CTRL = OFF_INV + (size_t)2 * T_TOK * 4;
  const size_t NEED     = OFF_CTRL + 1024;
  if (ws_size < NEED) return;

  __hip_bfloat16* xb   = (__hip_bfloat16*)(ws + OFF_XB);
  __hip_bfloat16* hbuf = (__hip_bfloat16*)(ws + OFF_H);
  float* parts     = (float*)(ws + OFF_PART);
  int*   slot_tok  = (int*)(ws + OFF_STOK);
  float* slot_prob = (float*)(ws + OFF_SPRB);
  int*   tk_e      = (int*)(ws + OFF_TKE);
  float* tk_p      = (float*)(ws + OFF_TKP);
  int*   inv       = (int*)(ws + OFF_INV);
  int*   ctrl      = (int*)(ws + OFF_CTRL);

  hipMemsetAsync(ctrl, 0, 1024, stream);
  hipMemsetAsync(slot_tok + 2 * T_TOK, 0, 128 * 4, stream);

  convert_x_kernel<<<(T_TOK * E_DIM) / (256 * 8), 256, 0, stream>>>(x, xb);
  router_kernel<<<T_TOK / 4, 256, 0, stream>>>(x, gk, tk_e, tk_p, ctrl);
  scanperm_kernel<<<1, 256, 0, stream>>>(tk_e, tk_p, ctrl, slot_tok, slot_prob, inv);
  gemm1_kernel<<<dim3(640), 512, 0, stream>>>(xb, w0, w1, ctrl, slot_tok, hbuf);
  gemm2_kernel<<<dim3(320), 512, 0, stream>>>(hbuf, wo, ctrl, slot_prob, parts);
  combine_kernel<<<(T_TOK * 128) / 256, 256, 0, stream>>>(parts, inv, out);
}